// Round 9
// baseline (903.666 us; speedup 1.0000x reference)
//
#include <hip/hip_runtime.h>
#include <stdint.h>
#include <stddef.h>

static constexpr int MM   = 2000;   // sites
static constexpr int NN   = 1000;   // states
static constexpr int NB2  = 32;     // 2B haplotype rows
static constexpr int DDIM = 5000;   // gexp dim
static constexpr int NPR  = 1008;   // F/S row stride in elements (63 lanes x 16)
static constexpr int NG   = 500;    // MM/4 groups
static constexpr float EAV = 0.991f; // (1-0.01) + 1/1000
static constexpr float EBV = 0.011f; // 0.01 + 1/1000

typedef uint32_t u32x4 __attribute__((ext_vector_type(4)));

__device__ __forceinline__ float rcp_fast(float x){ return __builtin_amdgcn_rcpf(x); }

__device__ __forceinline__ float tree16(const float* w){
  float a = ((w[0]+w[1]) + (w[2]+w[3])) + ((w[4]+w[5]) + (w[6]+w[7]));
  float b = ((w[8]+w[9]) + (w[10]+w[11])) + ((w[12]+w[13]) + (w[14]+w[15]));
  return a + b;
}

// Full-wave sum via DPP; result read from lane 63 into an SGPR (uniform).
// Verified on HW in Rounds 3/5/7 (absmax 0.0).
__device__ __forceinline__ float wave_total_sgpr(float v){
  int x;
  x = __builtin_amdgcn_update_dpp(0, __float_as_int(v), 0x111, 0xf, 0xf, true);  v += __int_as_float(x);
  x = __builtin_amdgcn_update_dpp(0, __float_as_int(v), 0x112, 0xf, 0xf, true);  v += __int_as_float(x);
  x = __builtin_amdgcn_update_dpp(0, __float_as_int(v), 0x114, 0xf, 0xf, true);  v += __int_as_float(x);
  x = __builtin_amdgcn_update_dpp(0, __float_as_int(v), 0x118, 0xf, 0xf, true);  v += __int_as_float(x);
  x = __builtin_amdgcn_update_dpp(0, __float_as_int(v), 0x142, 0xa, 0xf, false); v += __int_as_float(x);
  x = __builtin_amdgcn_update_dpp(0, __float_as_int(v), 0x143, 0xc, 0xf, false); v += __int_as_float(x);
  return __int_as_float(__builtin_amdgcn_readlane(__float_as_int(v), 63));
}

// Two independent full-wave sums, DPP stages interleaved (same 6-stage latency).
__device__ __forceinline__ void wave_total2(float &a, float &b){
  int xa, xb;
  xa = __builtin_amdgcn_update_dpp(0, __float_as_int(a), 0x111, 0xf, 0xf, true);
  xb = __builtin_amdgcn_update_dpp(0, __float_as_int(b), 0x111, 0xf, 0xf, true);
  a += __int_as_float(xa); b += __int_as_float(xb);
  xa = __builtin_amdgcn_update_dpp(0, __float_as_int(a), 0x112, 0xf, 0xf, true);
  xb = __builtin_amdgcn_update_dpp(0, __float_as_int(b), 0x112, 0xf, 0xf, true);
  a += __int_as_float(xa); b += __int_as_float(xb);
  xa = __builtin_amdgcn_update_dpp(0, __float_as_int(a), 0x114, 0xf, 0xf, true);
  xb = __builtin_amdgcn_update_dpp(0, __float_as_int(b), 0x114, 0xf, 0xf, true);
  a += __int_as_float(xa); b += __int_as_float(xb);
  xa = __builtin_amdgcn_update_dpp(0, __float_as_int(a), 0x118, 0xf, 0xf, true);
  xb = __builtin_amdgcn_update_dpp(0, __float_as_int(b), 0x118, 0xf, 0xf, true);
  a += __int_as_float(xa); b += __int_as_float(xb);
  xa = __builtin_amdgcn_update_dpp(0, __float_as_int(a), 0x142, 0xa, 0xf, false);
  xb = __builtin_amdgcn_update_dpp(0, __float_as_int(b), 0x142, 0xa, 0xf, false);
  a += __int_as_float(xa); b += __int_as_float(xb);
  xa = __builtin_amdgcn_update_dpp(0, __float_as_int(a), 0x143, 0xc, 0xf, false);
  xb = __builtin_amdgcn_update_dpp(0, __float_as_int(b), 0x143, 0xc, 0xf, false);
  a += __int_as_float(xa); b += __int_as_float(xb);
  a = __int_as_float(__builtin_amdgcn_readlane(__float_as_int(a), 63));
  b = __int_as_float(__builtin_amdgcn_readlane(__float_as_int(b), 63));
}

// ---------------- K0: pack ref bits + ref bytes + per-site popcount + obs bits -----
__global__ __launch_bounds__(64) void k_pack(const int* __restrict__ ref,
                                             const float* __restrict__ xoh,
                                             uint64_t* __restrict__ pack,
                                             uint4* __restrict__ refB4,
                                             float* __restrict__ cntf,
                                             uint32_t* __restrict__ obsw){
  int blk = blockIdx.x;
  int t = threadIdx.x;   // lane
  if (blk < NG){
    int g = blk;
    uint64_t wv = 0;
    for (int c = 0; c < 4; ++c){
      int i = g*4 + c;
      uint32_t m16 = 0;
      uint32_t d[4] = {0,0,0,0};
      #pragma unroll
      for (int j = 0; j < 16; ++j){
        int k = t*16 + j;
        uint32_t v = (k < NN) ? (uint32_t)(ref[(size_t)i*NN + k] & 1) : 0u;
        m16 |= v << j;
        d[j>>2] |= v << (8*(j&3));
      }
      wv |= (uint64_t)m16 << (16*c);
      refB4[(size_t)i*64 + t] = make_uint4(d[0],d[1],d[2],d[3]);
      float pc = wave_total_sgpr((float)__popc(m16));
      if (t == 0) cntf[i] = pc;
    }
    pack[(size_t)g*64 + t] = wv;
  } else {
    int b2 = t >> 1;
    int half = t & 1;
    for (int w = half*32; w < half*32 + 32; ++w){
      uint32_t word = 0;
      for (int z = 0; z < 32; ++z){
        int i = w*32 + z;
        if (i < MM){
          float x1 = xoh[(size_t)b2*MM*2 + (size_t)i*2 + 1];
          if (x1 > 0.5f) word |= 1u << z;
        }
      }
      obsw[b2*64 + w] = word;
    }
  }
}

// ---------------- K0b: forward scalar table (c0,c1,1-rn,rn/n) + E=sum(e) -----
__global__ __launch_bounds__(256) void k_prep2(const float* __restrict__ xoh,
                                               const float* __restrict__ recomb,
                                               const float* __restrict__ cntf,
                                               float4* __restrict__ FC4,
                                               float* __restrict__ FE){
  int idx = blockIdx.x*256 + threadIdx.x;
  if (idx < NB2*MM){
    int b2 = idx / MM, i = idx - b2*MM;
    float x1 = xoh[(size_t)b2*MM*2 + (size_t)i*2 + 1];
    bool obs = x1 > 0.5f;
    float c0 = obs ? EBV : EAV;
    float c1 = obs ? (EAV-EBV) : (EBV-EAV);
    float rn = (i+1 < MM) ? recomb[i+1] : 0.5f;
    FC4[(size_t)b2*MM + i] = make_float4(c0, c1, 1.0f - rn, rn/(float)NN);
    FE[(size_t)b2*MM + i]  = c0*(float)NN + c1*cntf[i];
  }
}

// ---------------- K1: GEMM partial ----------------
__global__ __launch_bounds__(256) void k_gemm(const float* __restrict__ gexp,
                                              const float* __restrict__ W,
                                              float* __restrict__ part){
  int cb = blockIdx.x;        // 0..7 column block
  int c  = blockIdx.y;        // 0..15 d-chunk
  int t  = threadIdx.x;
  int d0 = (c*DDIM) >> 4, d1 = ((c+1)*DDIM) >> 4;
  int len = d1 - d0;          // 312 or 313
  __shared__ __align__(16) float lg[313*20];
  for (int bb = 0; bb < 16; ++bb)
    for (int dd = t; dd < len; dd += 256)
      lg[dd*20 + bb] = gexp[(size_t)bb*DDIM + d0 + dd];
  __syncthreads();
  int i = cb*256 + t;
  if (i < MM){
    float acc[16];
    #pragma unroll
    for (int bb = 0; bb < 16; ++bb) acc[bb] = 0.f;
    for (int dd = 0; dd < len; ++dd){
      float w = W[(size_t)(d0 + dd)*MM + i];
      const float4* lp = (const float4*)&lg[dd*20];
      float4 g0 = lp[0], g1 = lp[1], g2 = lp[2], g3 = lp[3];
      acc[0]  += g0.x*w; acc[1]  += g0.y*w; acc[2]  += g0.z*w; acc[3]  += g0.w*w;
      acc[4]  += g1.x*w; acc[5]  += g1.y*w; acc[6]  += g1.z*w; acc[7]  += g1.w*w;
      acc[8]  += g2.x*w; acc[9]  += g2.y*w; acc[10] += g2.z*w; acc[11] += g2.w*w;
      acc[12] += g3.x*w; acc[13] += g3.y*w; acc[14] += g3.z*w; acc[15] += g3.w*w;
    }
    #pragma unroll
    for (int bb = 0; bb < 16; ++bb)
      part[((size_t)c*16 + bb)*MM + i] = acc[bb];
  }
}

// ---------------- K2: reduce partials -> logits; backward scalar table + E -----
__global__ __launch_bounds__(256) void k_gemmreduce(const float* __restrict__ part,
                                                    const float* __restrict__ bias,
                                                    const float* __restrict__ recomb,
                                                    const float* __restrict__ cntf,
                                                    float* __restrict__ acc,
                                                    float4* __restrict__ BC4,
                                                    float* __restrict__ BE){
  int idx = blockIdx.x*256 + threadIdx.x;
  if (idx < 16*MM){
    float s = 0.f;
    #pragma unroll
    for (int c = 0; c < 16; ++c) s += part[(size_t)c*16*MM + idx];
    acc[idx] = s;
    int bb = idx / MM, i = idx - bb*MM;
    float z = s + bias[i];
    float p = rcp_fast(1.0f + __expf(-z));
    float v0 = EAV + (EBV-EAV)*p;
    float v1 = EBV + (EAV-EBV)*p;
    float r = recomb[i];
    BC4[idx] = make_float4(v0, v1 - v0, 1.0f - r, r/(float)NN);
    BE[idx]  = v0*(float)NN + (v1 - v0)*cntf[i];
  }
}

// ---------------- K3: sequential chains, 2-site fused, deferred normalization ------
// Per pair (site1, site2):
//   g1 = W.e1, g12 = g1.e2 ; R1 = sum(g1), D12 = sum(g12)  [one interleaved DPP chain]
//   W1 = a1*g1 + b1*R1            (stored; state before site2)
//   R2 = a1*D12 + b1*E2*R1        (E2 = sum(e2), precomputed)
//   W2 = a2a1*g12 + (a2b1R1)*e2 + b2*R2   (folded into 2 fma/elem via e2=c0+c1*b)
// All stored states are scale-arbitrary (k_sites' per-site ratio cancels scale).
template<int DIR>
__device__ void run_chain(const uint4* __restrict__ refB4,
                          const float4* __restrict__ ctab,
                          const float* __restrict__ etab,
                          uint16_t* __restrict__ outp,
                          int b2, int lane){
  __shared__ __align__(16) float4 lds_ctab[MM + 32];
  __shared__ float lds_e[MM + 32];
  for (int idx = lane; idx < MM + 32; idx += 64){
    int site = idx - 16;
    site = (site < 0) ? 0 : ((site > MM-1) ? (MM-1) : site);
    lds_ctab[idx] = ctab[site];
    lds_e[idx] = etab[site];
  }
  __syncthreads();

  float t[16];
  #pragma unroll
  for (int j = 0; j < 16; ++j) t[j] = (lane*16 + j < NN) ? (1.0f/(float)NN) : 0.0f;
  const float mA = (lane < 63) ? 1.0f : 0.0f;   // states 1000..1023 stay exactly 0
  const float mB = (lane < 62) ? 1.0f : 0.0f;
  const bool doSt = lane < 63;                  // lane 63 is all-pad, never stored

  const ptrdiff_t rstep = (ptrdiff_t)DIR * 64;  // uint4 units per site
  const uint4* rp = refB4 + ((DIR > 0) ? 0 : (ptrdiff_t)(MM-1)*64) + lane;
  const ptrdiff_t ostep = (ptrdiff_t)DIR * NB2 * NPR;  // uint16 units per site
  uint16_t* op = outp + (size_t)b2*NPR
               + ((DIR > 0) ? (size_t)0 : (size_t)(MM-1)*(size_t)NB2*NPR)
               + (size_t)lane*16;

  uint4 A[8], Bv[8];
  #pragma unroll
  for (int k = 0; k < 8; ++k) A[k]  = rp[(ptrdiff_t)k*rstep];
  #pragma unroll
  for (int k = 0; k < 8; ++k) Bv[k] = rp[(ptrdiff_t)(k+8)*rstep];

  int ci = 16 + ((DIR > 0) ? 0 : (MM-1));   // LDS index of current site
  float Tlast = 1.0f;

  #pragma unroll 2
  for (int n = 0; n < MM/8; ++n){
    uint4 Cv[8];
    #pragma unroll
    for (int k = 0; k < 8; ++k) Cv[k] = rp[(ptrdiff_t)(8*n + 16 + k)*rstep];
    #pragma unroll
    for (int jp = 0; jp < 4; ++jp){
      const uint4 r1 = A[2*jp], r2 = A[2*jp+1];
      float4 s1 = lds_ctab[ci];
      float4 s2 = lds_ctab[ci + DIR];
      float  E2 = lds_e[ci + DIR];
      // ---- store F_s = t (truncated bf16, scale-free) ----
      if (doSt){
        uint32_t d[8];
        #pragma unroll
        for (int q = 0; q < 8; ++q)
          d[q] = __builtin_amdgcn_perm(__float_as_uint(t[2*q+1]), __float_as_uint(t[2*q]), 0x07060302u);
        u32x4* dp = (u32x4*)op;
        u32x4 v0; v0.x = d[0]; v0.y = d[1]; v0.z = d[2]; v0.w = d[3];
        u32x4 v1; v1.x = d[4]; v1.y = d[5]; v1.z = d[6]; v1.w = d[7];
        dp[0] = v0; dp[1] = v1;
      }
      op += ostep;
      // ---- g1 = t.e1 ; g12 = g1.e2 ----
      uint32_t w1b[4] = {r1.x, r1.y, r1.z, r1.w};
      uint32_t w2b[4] = {r2.x, r2.y, r2.z, r2.w};
      float b2f[16], g1[16], g12[16];
      #pragma unroll
      for (int q = 0; q < 4; ++q){
        float a0 = (float)( w1b[q]        & 0xFFu);
        float a1 = (float)((w1b[q] >> 8)  & 0xFFu);
        float a2 = (float)((w1b[q] >> 16) & 0xFFu);
        float a3 = (float)( w1b[q] >> 24);
        b2f[4*q+0] = (float)( w2b[q]        & 0xFFu);
        b2f[4*q+1] = (float)((w2b[q] >> 8)  & 0xFFu);
        b2f[4*q+2] = (float)((w2b[q] >> 16) & 0xFFu);
        b2f[4*q+3] = (float)( w2b[q] >> 24);
        g1[4*q+0] = t[4*q+0] * (s1.x + s1.y * a0);
        g1[4*q+1] = t[4*q+1] * (s1.x + s1.y * a1);
        g1[4*q+2] = t[4*q+2] * (s1.x + s1.y * a2);
        g1[4*q+3] = t[4*q+3] * (s1.x + s1.y * a3);
        g12[4*q+0] = g1[4*q+0] * (s2.x + s2.y * b2f[4*q+0]);
        g12[4*q+1] = g1[4*q+1] * (s2.x + s2.y * b2f[4*q+1]);
        g12[4*q+2] = g1[4*q+2] * (s2.x + s2.y * b2f[4*q+2]);
        g12[4*q+3] = g1[4*q+3] * (s2.x + s2.y * b2f[4*q+3]);
      }
      float R1  = tree16(g1);
      float D12 = tree16(g12);
      wave_total2(R1, D12);
      // ---- W1 = a1*g1 + b1*R1 (masked), store as F_{s+1} ----
      float bR = s1.w * R1;
      float w1A = bR * mA, w1B = bR * mB;
      if (doSt){
        float w1[16];
        #pragma unroll
        for (int j = 0; j < 8; ++j)  w1[j] = g1[j]*s1.z + w1A;
        #pragma unroll
        for (int j = 8; j < 16; ++j) w1[j] = g1[j]*s1.z + w1B;
        uint32_t d[8];
        #pragma unroll
        for (int q = 0; q < 8; ++q)
          d[q] = __builtin_amdgcn_perm(__float_as_uint(w1[2*q+1]), __float_as_uint(w1[2*q]), 0x07060302u);
        u32x4* dp = (u32x4*)op;
        u32x4 v0; v0.x = d[0]; v0.y = d[1]; v0.z = d[2]; v0.w = d[3];
        u32x4 v1; v1.x = d[4]; v1.y = d[5]; v1.z = d[6]; v1.w = d[7];
        dp[0] = v0; dp[1] = v1;
      }
      op += ostep;
      // ---- W2 = a2a1*g12 + (a2b1R1)*e2 + b2*R2 ----
      float R2 = s1.z*D12 + (s1.w*E2)*R1;
      float A2 = s2.z*s1.z;
      float U  = (s2.z*s1.w)*R1;
      float sb = U*s2.y;
      float scv = U*s2.x + s2.w*R2;
      float scA = scv*mA, scB = scv*mB;
      #pragma unroll
      for (int j = 0; j < 8; ++j)  t[j] = g12[j]*A2 + (b2f[j]*sb + scA);
      #pragma unroll
      for (int j = 8; j < 16; ++j) t[j] = g12[j]*A2 + (b2f[j]*sb + scB);
      Tlast = R2;
      ci += 2*DIR;
    }
    // ---- periodic renorm (range only; scale cancels downstream) ----
    float rs = rcp_fast(Tlast);
    #pragma unroll
    for (int j = 0; j < 16; ++j) t[j] *= rs;
    Tlast = 1.0f;
    #pragma unroll
    for (int k = 0; k < 8; ++k){ A[k] = Bv[k]; Bv[k] = Cv[k]; }
  }
}

__global__ __launch_bounds__(64, 1) void k_chains(const uint4* __restrict__ refB4,
                                                  const float4* __restrict__ FC4,
                                                  const float4* __restrict__ BC4,
                                                  const float* __restrict__ FE,
                                                  const float* __restrict__ BE,
                                                  uint16_t* __restrict__ F,
                                                  uint16_t* __restrict__ S){
  int lane = threadIdx.x;
  int blk  = blockIdx.x;
  int b2   = blk & 31;
  if (blk < 32) run_chain<1>(refB4, FC4 + (size_t)b2*MM, FE + (size_t)b2*MM, F, b2, lane);
  else          run_chain<-1>(refB4, BC4 + (size_t)(b2>>1)*MM, BE + (size_t)(b2>>1)*MM, S, b2, lane);
}

// ---------------- K4: per-site p_xe terms (fully parallel). wave per (i,b2). ----------
__global__ __launch_bounds__(256) void k_sites(const uint16_t* __restrict__ F,
                                               const uint16_t* __restrict__ S,
                                               const uint64_t* __restrict__ pack,
                                               const uint32_t* __restrict__ obsw,
                                               const float* __restrict__ acc,
                                               const float* __restrict__ bias,
                                               float* __restrict__ terms){
  int lane = threadIdx.x & 63;
  int wid  = threadIdx.x >> 6;
  int s    = blockIdx.x*4 + wid;     // 0 .. 63999
  int i    = s >> 5;
  int b2   = s & 31;
  uint4 f0 = make_uint4(0,0,0,0), f1 = f0, s0 = f0, s1 = f0;
  if (lane < 63){
    size_t off = ((size_t)i*NB2 + b2)*NPR + lane*16;
    const uint4* fp = (const uint4*)(F + off);
    const uint4* sp = (const uint4*)(S + off);
    f0 = fp[0]; f1 = fp[1];
    s0 = sp[0]; s1 = sp[1];
  }
  uint32_t m16 = (uint32_t)(pack[(size_t)(i>>2)*64 + lane] >> (16*(i&3))) & 0xFFFFu;

  uint32_t fa[8] = {f0.x,f0.y,f0.z,f0.w,f1.x,f1.y,f1.z,f1.w};
  uint32_t sa[8] = {s0.x,s0.y,s0.z,s0.w,s1.x,s1.y,s1.z,s1.w};
  float Tt = 0.f, Tb = 0.f;
  #pragma unroll
  for (int q = 0; q < 8; ++q){
    float flo = __uint_as_float(fa[q] << 16);
    float fhi = __uint_as_float(fa[q] & 0xFFFF0000u);
    float slo = __uint_as_float(sa[q] << 16);
    float shi = __uint_as_float(sa[q] & 0xFFFF0000u);
    float pl = flo*slo, ph = fhi*shi;
    Tt += pl + ph;
    Tb += (((m16 >> (2*q)) & 1u) ? pl : 0.f) + (((m16 >> (2*q+1)) & 1u) ? ph : 0.f);
  }
  wave_total2(Tt, Tb);
  if (lane == 0){
    uint32_t obsb = (obsw[b2*64 + (i>>5)] >> (i & 31)) & 1u;
    float z = acc[(size_t)(b2 >> 1)*MM + i] + bias[i];
    float p = rcp_fast(1.0f + __expf(-z));
    float A = Tt - Tb, B = Tb;
    float d0 = EAV*A + EBV*B;
    float d1 = EBV*A + EAV*B;
    float w0 = d0*(1.0f - p), w1 = d1*p;
    float term = __logf((obsb ? w1 : w0) * rcp_fast(w0 + w1));
    terms[s] = term;
  }
}

// ---------------- K5: final reduction ----------
__global__ __launch_bounds__(256) void k_final(const float* __restrict__ terms,
                                               float* __restrict__ out){
  __shared__ float red[256];
  float s = 0.f;
  for (int idx = threadIdx.x; idx < MM*NB2; idx += 256) s += terms[idx];
  red[threadIdx.x] = s;
  __syncthreads();
  for (int st = 128; st > 0; st >>= 1){
    if (threadIdx.x < st) red[threadIdx.x] += red[threadIdx.x + st];
    __syncthreads();
  }
  if (threadIdx.x == 0) out[0] = -red[0];
}

extern "C" void kernel_launch(void* const* d_in, const int* in_sizes, int n_in,
                              void* d_out, int out_size, void* d_ws, size_t ws_size,
                              hipStream_t stream){
  const float* gexp   = (const float*)d_in[0];   // [16,5000]
  const float* xoh    = (const float*)d_in[1];   // [32,2000,2]
  const float* W      = (const float*)d_in[2];   // [5000,2000]
  const float* bias   = (const float*)d_in[3];   // [2000]
  const int*   ref    = (const int*)d_in[4];     // [2000,1000]
  const float* recomb = (const float*)d_in[5];   // [2000]
  float* out = (float*)d_out;
  char* ws = (char*)d_ws;

  // Total footprint 264,752,960 B — below Round-1 proven 264,840,192 B.
  const size_t stateBytes = (size_t)MM*NB2*NPR*2;      // 129,024,000 per array (bf16)
  size_t offF    = 0;
  size_t offS    = offF + stateBytes;                  // 129,024,000
  size_t offPack = offS + stateBytes;                  // 258,048,000
  size_t offObs  = offPack + (size_t)NG*64*8;          // 258,304,000
  size_t offPart = offObs + 32*64*4;                   // 258,312,192
  size_t offAcc  = offPart + (size_t)16*16*MM*4;       // 260,360,192
  size_t offTerm = offAcc + (size_t)16*MM*4;           // 260,488,192
  size_t offRefB = offTerm + (size_t)MM*NB2*4;         // 260,744,192
  size_t offFC4  = offRefB + (size_t)(MM+32)*1024;     // 262,824,960
  size_t offBC4  = offFC4 + (size_t)NB2*MM*16;         // 263,848,960
  size_t offCnt  = offBC4 + (size_t)16*MM*16;          // 264,360,960
  size_t offFE   = offCnt + (size_t)MM*4;              // 264,368,960
  size_t offBE   = offFE + (size_t)NB2*MM*4;           // 264,624,960 (+128,000 = 264,752,960)

  uint16_t* Fb   = (uint16_t*)(ws + offF);
  uint16_t* Sb   = (uint16_t*)(ws + offS);
  uint64_t* pack = (uint64_t*)(ws + offPack);
  uint32_t* obsw = (uint32_t*)(ws + offObs);
  float*    part = (float*)(ws + offPart);
  float*    accp = (float*)(ws + offAcc);
  float*    term = (float*)(ws + offTerm);
  uint4*    refB = (uint4*)(ws + offRefB) + 16*64;     // site 0, pad +/-16 sites
  float4*   FC4  = (float4*)(ws + offFC4);
  float4*   BC4  = (float4*)(ws + offBC4);
  float*    cntf = (float*)(ws + offCnt);
  float*    FE   = (float*)(ws + offFE);
  float*    BE   = (float*)(ws + offBE);

  hipLaunchKernelGGL(k_pack, dim3(NG+1), dim3(64), 0, stream, ref, xoh, pack, refB, cntf, obsw);
  hipLaunchKernelGGL(k_prep2, dim3((NB2*MM+255)/256), dim3(256), 0, stream, xoh, recomb, cntf, FC4, FE);
  hipLaunchKernelGGL(k_gemm, dim3(8,16), dim3(256), 0, stream, gexp, W, part);
  hipLaunchKernelGGL(k_gemmreduce, dim3(125), dim3(256), 0, stream, part, bias, recomb, cntf, accp, BC4, BE);
  hipLaunchKernelGGL(k_chains, dim3(64), dim3(64), 0, stream, refB, FC4, BC4, FE, BE, Fb, Sb);
  hipLaunchKernelGGL(k_sites, dim3(MM*NB2/4), dim3(256), 0, stream, Fb, Sb, pack, obsw, accp, bias, term);
  hipLaunchKernelGGL(k_final, dim3(1), dim3(256), 0, stream, term, out);
}

// Round 10
// 825.675 us; speedup vs baseline: 1.0945x; 1.0945x over previous
//
#include <hip/hip_runtime.h>
#include <stdint.h>
#include <stddef.h>

static constexpr int MM   = 2000;   // sites
static constexpr int NN   = 1000;   // states
static constexpr int NB2  = 32;     // 2B haplotype rows
static constexpr int DDIM = 5000;   // gexp dim
static constexpr int NPR  = 1008;   // F/S row stride in elements (63 lanes x 16)
static constexpr int NG   = 500;    // MM/4 groups
static constexpr float EAV = 0.991f; // (1-0.01) + 1/1000
static constexpr float EBV = 0.011f; // 0.01 + 1/1000

typedef uint32_t u32x4 __attribute__((ext_vector_type(4)));
typedef float    f32x2 __attribute__((ext_vector_type(2)));

__device__ __forceinline__ float rcp_fast(float x){ return __builtin_amdgcn_rcpf(x); }

// Full-wave sum via DPP; result read from lane 63 into an SGPR (uniform).
// Verified on HW in Rounds 3/5/7/9 (absmax 0.0).
__device__ __forceinline__ float wave_total_sgpr(float v){
  int x;
  x = __builtin_amdgcn_update_dpp(0, __float_as_int(v), 0x111, 0xf, 0xf, true);  v += __int_as_float(x);
  x = __builtin_amdgcn_update_dpp(0, __float_as_int(v), 0x112, 0xf, 0xf, true);  v += __int_as_float(x);
  x = __builtin_amdgcn_update_dpp(0, __float_as_int(v), 0x114, 0xf, 0xf, true);  v += __int_as_float(x);
  x = __builtin_amdgcn_update_dpp(0, __float_as_int(v), 0x118, 0xf, 0xf, true);  v += __int_as_float(x);
  x = __builtin_amdgcn_update_dpp(0, __float_as_int(v), 0x142, 0xa, 0xf, false); v += __int_as_float(x);
  x = __builtin_amdgcn_update_dpp(0, __float_as_int(v), 0x143, 0xc, 0xf, false); v += __int_as_float(x);
  return __int_as_float(__builtin_amdgcn_readlane(__float_as_int(v), 63));
}

// Two independent full-wave sums, DPP stages interleaved.
__device__ __forceinline__ void wave_total2(float &a, float &b){
  int xa, xb;
  xa = __builtin_amdgcn_update_dpp(0, __float_as_int(a), 0x111, 0xf, 0xf, true);
  xb = __builtin_amdgcn_update_dpp(0, __float_as_int(b), 0x111, 0xf, 0xf, true);
  a += __int_as_float(xa); b += __int_as_float(xb);
  xa = __builtin_amdgcn_update_dpp(0, __float_as_int(a), 0x112, 0xf, 0xf, true);
  xb = __builtin_amdgcn_update_dpp(0, __float_as_int(b), 0x112, 0xf, 0xf, true);
  a += __int_as_float(xa); b += __int_as_float(xb);
  xa = __builtin_amdgcn_update_dpp(0, __float_as_int(a), 0x114, 0xf, 0xf, true);
  xb = __builtin_amdgcn_update_dpp(0, __float_as_int(b), 0x114, 0xf, 0xf, true);
  a += __int_as_float(xa); b += __int_as_float(xb);
  xa = __builtin_amdgcn_update_dpp(0, __float_as_int(a), 0x118, 0xf, 0xf, true);
  xb = __builtin_amdgcn_update_dpp(0, __float_as_int(b), 0x118, 0xf, 0xf, true);
  a += __int_as_float(xa); b += __int_as_float(xb);
  xa = __builtin_amdgcn_update_dpp(0, __float_as_int(a), 0x142, 0xa, 0xf, false);
  xb = __builtin_amdgcn_update_dpp(0, __float_as_int(b), 0x142, 0xa, 0xf, false);
  a += __int_as_float(xa); b += __int_as_float(xb);
  xa = __builtin_amdgcn_update_dpp(0, __float_as_int(a), 0x143, 0xc, 0xf, false);
  xb = __builtin_amdgcn_update_dpp(0, __float_as_int(b), 0x143, 0xc, 0xf, false);
  a += __int_as_float(xa); b += __int_as_float(xb);
  a = __int_as_float(__builtin_amdgcn_readlane(__float_as_int(a), 63));
  b = __int_as_float(__builtin_amdgcn_readlane(__float_as_int(b), 63));
}

// ---------------- K0: pack ref bits + ref bytes + per-site popcount + obs bits -----
__global__ __launch_bounds__(64) void k_pack(const int* __restrict__ ref,
                                             const float* __restrict__ xoh,
                                             uint64_t* __restrict__ pack,
                                             uint4* __restrict__ refB4,
                                             float* __restrict__ cntf,
                                             uint32_t* __restrict__ obsw){
  int blk = blockIdx.x;
  int t = threadIdx.x;   // lane
  if (blk < NG){
    int g = blk;
    uint64_t wv = 0;
    for (int c = 0; c < 4; ++c){
      int i = g*4 + c;
      uint32_t m16 = 0;
      uint32_t d[4] = {0,0,0,0};
      #pragma unroll
      for (int j = 0; j < 16; ++j){
        int k = t*16 + j;
        uint32_t v = (k < NN) ? (uint32_t)(ref[(size_t)i*NN + k] & 1) : 0u;
        m16 |= v << j;
        d[j>>2] |= v << (8*(j&3));
      }
      wv |= (uint64_t)m16 << (16*c);
      refB4[(size_t)i*64 + t] = make_uint4(d[0],d[1],d[2],d[3]);
      float pc = wave_total_sgpr((float)__popc(m16));
      if (t == 0) cntf[i] = pc;
    }
    pack[(size_t)g*64 + t] = wv;
  } else {
    int b2 = t >> 1;
    int half = t & 1;
    for (int w = half*32; w < half*32 + 32; ++w){
      uint32_t word = 0;
      for (int z = 0; z < 32; ++z){
        int i = w*32 + z;
        if (i < MM){
          float x1 = xoh[(size_t)b2*MM*2 + (size_t)i*2 + 1];
          if (x1 > 0.5f) word |= 1u << z;
        }
      }
      obsw[b2*64 + w] = word;
    }
  }
}

// ---------------- K0b: forward scalar table (c0,c1,1-rn,rn/n) + E=sum(e) -----
__global__ __launch_bounds__(256) void k_prep2(const float* __restrict__ xoh,
                                               const float* __restrict__ recomb,
                                               const float* __restrict__ cntf,
                                               float4* __restrict__ FC4,
                                               float* __restrict__ FE){
  int idx = blockIdx.x*256 + threadIdx.x;
  if (idx < NB2*MM){
    int b2 = idx / MM, i = idx - b2*MM;
    float x1 = xoh[(size_t)b2*MM*2 + (size_t)i*2 + 1];
    bool obs = x1 > 0.5f;
    float c0 = obs ? EBV : EAV;
    float c1 = obs ? (EAV-EBV) : (EBV-EAV);
    float rn = (i+1 < MM) ? recomb[i+1] : 0.5f;
    FC4[(size_t)b2*MM + i] = make_float4(c0, c1, 1.0f - rn, rn/(float)NN);
    FE[(size_t)b2*MM + i]  = c0*(float)NN + c1*cntf[i];
  }
}

// ---------------- K1: GEMM partial ----------------
__global__ __launch_bounds__(256) void k_gemm(const float* __restrict__ gexp,
                                              const float* __restrict__ W,
                                              float* __restrict__ part){
  int cb = blockIdx.x;        // 0..7 column block
  int c  = blockIdx.y;        // 0..15 d-chunk
  int t  = threadIdx.x;
  int d0 = (c*DDIM) >> 4, d1 = ((c+1)*DDIM) >> 4;
  int len = d1 - d0;          // 312 or 313
  __shared__ __align__(16) float lg[313*20];
  for (int bb = 0; bb < 16; ++bb)
    for (int dd = t; dd < len; dd += 256)
      lg[dd*20 + bb] = gexp[(size_t)bb*DDIM + d0 + dd];
  __syncthreads();
  int i = cb*256 + t;
  if (i < MM){
    float acc[16];
    #pragma unroll
    for (int bb = 0; bb < 16; ++bb) acc[bb] = 0.f;
    for (int dd = 0; dd < len; ++dd){
      float w = W[(size_t)(d0 + dd)*MM + i];
      const float4* lp = (const float4*)&lg[dd*20];
      float4 g0 = lp[0], g1 = lp[1], g2 = lp[2], g3 = lp[3];
      acc[0]  += g0.x*w; acc[1]  += g0.y*w; acc[2]  += g0.z*w; acc[3]  += g0.w*w;
      acc[4]  += g1.x*w; acc[5]  += g1.y*w; acc[6]  += g1.z*w; acc[7]  += g1.w*w;
      acc[8]  += g2.x*w; acc[9]  += g2.y*w; acc[10] += g2.z*w; acc[11] += g2.w*w;
      acc[12] += g3.x*w; acc[13] += g3.y*w; acc[14] += g3.z*w; acc[15] += g3.w*w;
    }
    #pragma unroll
    for (int bb = 0; bb < 16; ++bb)
      part[((size_t)c*16 + bb)*MM + i] = acc[bb];
  }
}

// ---------------- K2: reduce partials -> logits; backward scalar table + E -----
__global__ __launch_bounds__(256) void k_gemmreduce(const float* __restrict__ part,
                                                    const float* __restrict__ bias,
                                                    const float* __restrict__ recomb,
                                                    const float* __restrict__ cntf,
                                                    float* __restrict__ acc,
                                                    float4* __restrict__ BC4,
                                                    float* __restrict__ BE){
  int idx = blockIdx.x*256 + threadIdx.x;
  if (idx < 16*MM){
    float s = 0.f;
    #pragma unroll
    for (int c = 0; c < 16; ++c) s += part[(size_t)c*16*MM + idx];
    acc[idx] = s;
    int bb = idx / MM, i = idx - bb*MM;
    float z = s + bias[i];
    float p = rcp_fast(1.0f + __expf(-z));
    float v0 = EAV + (EBV-EAV)*p;
    float v1 = EBV + (EAV-EBV)*p;
    float r = recomb[i];
    BC4[idx] = make_float4(v0, v1 - v0, 1.0f - r, r/(float)NN);
    BE[idx]  = v0*(float)NN + (v1 - v0)*cntf[i];
  }
}

// ---------------- K3: sequential chains, deferred normalization, packed f32x2 ------
// W' = (1-r)*g + (r/n)*R with g = W.e, R = sum(g). States scale-arbitrary
// (k_sites' per-site ratio cancels scale); renorm every 8 sites for range.
// Elementwise math in f32x2 (v_pk_fma_f32 / v_pk_mul_f32 / v_pk_add_f32):
// halves the VALU instruction count on the latency-serialized lone wave.
template<int DIR>
__device__ void run_chain(const uint4* __restrict__ refB4,
                          const float4* __restrict__ ctab,
                          uint16_t* __restrict__ outp,
                          int b2, int lane){
  __shared__ __align__(16) float4 lds_ctab[MM];
  for (int idx = lane; idx < MM; idx += 64) lds_ctab[idx] = ctab[idx];
  __syncthreads();

  f32x2 t[8];
  #pragma unroll
  for (int q = 0; q < 8; ++q){
    t[q].x = (lane*16 + 2*q     < NN) ? (1.0f/(float)NN) : 0.0f;
    t[q].y = (lane*16 + 2*q + 1 < NN) ? (1.0f/(float)NN) : 0.0f;
  }
  const float mA = (lane < 63) ? 1.0f : 0.0f;   // elems 0..7: states stay 0 on pads
  const float mB = (lane < 62) ? 1.0f : 0.0f;   // elems 8..15
  const bool doSt = lane < 63;                  // lane 63 is all-pad, never stored

  const ptrdiff_t rstep = (ptrdiff_t)DIR * 64;  // uint4 units per site
  const uint4* rp = refB4 + ((DIR > 0) ? 0 : (ptrdiff_t)(MM-1)*64) + lane;
  const ptrdiff_t ostep = (ptrdiff_t)DIR * NB2 * NPR;  // uint16 units per site
  uint16_t* op = outp + (size_t)b2*NPR
               + ((DIR > 0) ? (size_t)0 : (size_t)(MM-1)*(size_t)NB2*NPR)
               + (size_t)lane*16;

  uint4 A[8], Bv[8];
  #pragma unroll
  for (int k = 0; k < 8; ++k) A[k]  = rp[(ptrdiff_t)k*rstep];
  #pragma unroll
  for (int k = 0; k < 8; ++k) Bv[k] = rp[(ptrdiff_t)(k+8)*rstep];

  int ci = (DIR > 0) ? 0 : (MM-1);   // ctab index of current site
  float Tlast = 1.0f;

  #pragma unroll 2
  for (int n = 0; n < MM/8; ++n){
    uint4 Cv[8];
    #pragma unroll
    for (int k = 0; k < 8; ++k) Cv[k] = rp[(ptrdiff_t)(8*n + 16 + k)*rstep];
    #pragma unroll
    for (int k = 0; k < 8; ++k){
      float4 sc4 = lds_ctab[ci];
      // ---- store W (pre-site state) as truncated bf16 (scale-free) ----
      if (doSt){
        uint32_t d[8];
        #pragma unroll
        for (int q = 0; q < 8; ++q)
          d[q] = __builtin_amdgcn_perm(__float_as_uint(t[q].y), __float_as_uint(t[q].x), 0x07060302u);
        u32x4* dp = (u32x4*)op;
        u32x4 v0; v0.x = d[0]; v0.y = d[1]; v0.z = d[2]; v0.w = d[3];
        u32x4 v1; v1.x = d[4]; v1.y = d[5]; v1.z = d[6]; v1.w = d[7];
        dp[0] = v0; dp[1] = v1;
      }
      op += ostep;
      // ---- g = W * e  (e = c0 + c1*b; byte->float cvt + pk fma/mul) ----
      uint32_t rw[4] = {A[k].x, A[k].y, A[k].z, A[k].w};
      f32x2 c0p; c0p.x = sc4.x; c0p.y = sc4.x;
      f32x2 c1p; c1p.x = sc4.y; c1p.y = sc4.y;
      f32x2 g[8];
      #pragma unroll
      for (int q = 0; q < 4; ++q){
        f32x2 b01, b23;
        b01.x = (float)( rw[q]        & 0xFFu);   // v_cvt_f32_ubyte0
        b01.y = (float)((rw[q] >> 8)  & 0xFFu);   // v_cvt_f32_ubyte1
        b23.x = (float)((rw[q] >> 16) & 0xFFu);   // v_cvt_f32_ubyte2
        b23.y = (float)( rw[q] >> 24);            // v_cvt_f32_ubyte3
        g[2*q]   = t[2*q]   * (c0p + c1p*b01);
        g[2*q+1] = t[2*q+1] * (c0p + c1p*b23);
      }
      f32x2 s0 = (g[0]+g[1]) + (g[2]+g[3]);
      f32x2 s1 = (g[4]+g[5]) + (g[6]+g[7]);
      f32x2 ss = s0 + s1;
      float R = wave_total_sgpr(ss.x + ss.y);
      // ---- W' = (1-r)*g + (r/n)*R  (masked add keeps pad states at 0) ----
      float aA = (R * sc4.w) * mA;
      float aB = (R * sc4.w) * mB;
      f32x2 az;  az.x  = sc4.z; az.y  = sc4.z;
      f32x2 adA; adA.x = aA;    adA.y = aA;
      f32x2 adB; adB.x = aB;    adB.y = aB;
      #pragma unroll
      for (int q = 0; q < 4; ++q) t[q] = g[q]*az + adA;
      #pragma unroll
      for (int q = 4; q < 8; ++q) t[q] = g[q]*az + adB;
      Tlast = R;
      ci += DIR;
    }
    // ---- periodic renorm (range only; scale cancels downstream) ----
    float rs = rcp_fast(Tlast);
    f32x2 rsp; rsp.x = rs; rsp.y = rs;
    #pragma unroll
    for (int q = 0; q < 8; ++q) t[q] = t[q] * rsp;
    Tlast = 1.0f;
    #pragma unroll
    for (int k = 0; k < 8; ++k){ A[k] = Bv[k]; Bv[k] = Cv[k]; }
  }
}

__global__ __launch_bounds__(64, 1) void k_chains(const uint4* __restrict__ refB4,
                                                  const float4* __restrict__ FC4,
                                                  const float4* __restrict__ BC4,
                                                  const float* __restrict__ FE,
                                                  const float* __restrict__ BE,
                                                  uint16_t* __restrict__ F,
                                                  uint16_t* __restrict__ S){
  int lane = threadIdx.x;
  int blk  = blockIdx.x;
  int b2   = blk & 31;
  (void)FE; (void)BE;
  if (blk < 32) run_chain<1>(refB4, FC4 + (size_t)b2*MM, F, b2, lane);
  else          run_chain<-1>(refB4, BC4 + (size_t)(b2>>1)*MM, S, b2, lane);
}

// ---------------- K4: per-site p_xe terms (fully parallel). wave per (i,b2). ----------
__global__ __launch_bounds__(256) void k_sites(const uint16_t* __restrict__ F,
                                               const uint16_t* __restrict__ S,
                                               const uint64_t* __restrict__ pack,
                                               const uint32_t* __restrict__ obsw,
                                               const float* __restrict__ acc,
                                               const float* __restrict__ bias,
                                               float* __restrict__ terms){
  int lane = threadIdx.x & 63;
  int wid  = threadIdx.x >> 6;
  int s    = blockIdx.x*4 + wid;     // 0 .. 63999
  int i    = s >> 5;
  int b2   = s & 31;
  uint4 f0 = make_uint4(0,0,0,0), f1 = f0, s0 = f0, s1 = f0;
  if (lane < 63){
    size_t off = ((size_t)i*NB2 + b2)*NPR + lane*16;
    const uint4* fp = (const uint4*)(F + off);
    const uint4* sp = (const uint4*)(S + off);
    f0 = fp[0]; f1 = fp[1];
    s0 = sp[0]; s1 = sp[1];
  }
  uint32_t m16 = (uint32_t)(pack[(size_t)(i>>2)*64 + lane] >> (16*(i&3))) & 0xFFFFu;

  uint32_t fa[8] = {f0.x,f0.y,f0.z,f0.w,f1.x,f1.y,f1.z,f1.w};
  uint32_t sa[8] = {s0.x,s0.y,s0.z,s0.w,s1.x,s1.y,s1.z,s1.w};
  float Tt = 0.f, Tb = 0.f;
  #pragma unroll
  for (int q = 0; q < 8; ++q){
    float flo = __uint_as_float(fa[q] << 16);
    float fhi = __uint_as_float(fa[q] & 0xFFFF0000u);
    float slo = __uint_as_float(sa[q] << 16);
    float shi = __uint_as_float(sa[q] & 0xFFFF0000u);
    float pl = flo*slo, ph = fhi*shi;
    Tt += pl + ph;
    Tb += (((m16 >> (2*q)) & 1u) ? pl : 0.f) + (((m16 >> (2*q+1)) & 1u) ? ph : 0.f);
  }
  wave_total2(Tt, Tb);
  if (lane == 0){
    uint32_t obsb = (obsw[b2*64 + (i>>5)] >> (i & 31)) & 1u;
    float z = acc[(size_t)(b2 >> 1)*MM + i] + bias[i];
    float p = rcp_fast(1.0f + __expf(-z));
    float A = Tt - Tb, B = Tb;
    float d0 = EAV*A + EBV*B;
    float d1 = EBV*A + EAV*B;
    float w0 = d0*(1.0f - p), w1 = d1*p;
    float term = __logf((obsb ? w1 : w0) * rcp_fast(w0 + w1));
    terms[s] = term;
  }
}

// ---------------- K5: final reduction ----------
__global__ __launch_bounds__(256) void k_final(const float* __restrict__ terms,
                                               float* __restrict__ out){
  __shared__ float red[256];
  float s = 0.f;
  for (int idx = threadIdx.x; idx < MM*NB2; idx += 256) s += terms[idx];
  red[threadIdx.x] = s;
  __syncthreads();
  for (int st = 128; st > 0; st >>= 1){
    if (threadIdx.x < st) red[threadIdx.x] += red[threadIdx.x + st];
    __syncthreads();
  }
  if (threadIdx.x == 0) out[0] = -red[0];
}

extern "C" void kernel_launch(void* const* d_in, const int* in_sizes, int n_in,
                              void* d_out, int out_size, void* d_ws, size_t ws_size,
                              hipStream_t stream){
  const float* gexp   = (const float*)d_in[0];   // [16,5000]
  const float* xoh    = (const float*)d_in[1];   // [32,2000,2]
  const float* W      = (const float*)d_in[2];   // [5000,2000]
  const float* bias   = (const float*)d_in[3];   // [2000]
  const int*   ref    = (const int*)d_in[4];     // [2000,1000]
  const float* recomb = (const float*)d_in[5];   // [2000]
  float* out = (float*)d_out;
  char* ws = (char*)d_ws;

  // Total footprint 264,752,960 B — below Round-1 proven 264,840,192 B.
  const size_t stateBytes = (size_t)MM*NB2*NPR*2;      // 129,024,000 per array (bf16)
  size_t offF    = 0;
  size_t offS    = offF + stateBytes;                  // 129,024,000
  size_t offPack = offS + stateBytes;                  // 258,048,000
  size_t offObs  = offPack + (size_t)NG*64*8;          // 258,304,000
  size_t offPart = offObs + 32*64*4;                   // 258,312,192
  size_t offAcc  = offPart + (size_t)16*16*MM*4;       // 260,360,192
  size_t offTerm = offAcc + (size_t)16*MM*4;           // 260,488,192
  size_t offRefB = offTerm + (size_t)MM*NB2*4;         // 260,744,192
  size_t offFC4  = offRefB + (size_t)(MM+32)*1024;     // 262,824,960
  size_t offBC4  = offFC4 + (size_t)NB2*MM*16;         // 263,848,960
  size_t offCnt  = offBC4 + (size_t)16*MM*16;          // 264,360,960
  size_t offFE   = offCnt + (size_t)MM*4;              // 264,368,960
  size_t offBE   = offFE + (size_t)NB2*MM*4;           // 264,624,960 (+128,000 = 264,752,960)

  uint16_t* Fb   = (uint16_t*)(ws + offF);
  uint16_t* Sb   = (uint16_t*)(ws + offS);
  uint64_t* pack = (uint64_t*)(ws + offPack);
  uint32_t* obsw = (uint32_t*)(ws + offObs);
  float*    part = (float*)(ws + offPart);
  float*    accp = (float*)(ws + offAcc);
  float*    term = (float*)(ws + offTerm);
  uint4*    refB = (uint4*)(ws + offRefB) + 16*64;     // site 0, pad +/-16 sites
  float4*   FC4  = (float4*)(ws + offFC4);
  float4*   BC4  = (float4*)(ws + offBC4);
  float*    cntf = (float*)(ws + offCnt);
  float*    FE   = (float*)(ws + offFE);
  float*    BE   = (float*)(ws + offBE);

  hipLaunchKernelGGL(k_pack, dim3(NG+1), dim3(64), 0, stream, ref, xoh, pack, refB, cntf, obsw);
  hipLaunchKernelGGL(k_prep2, dim3((NB2*MM+255)/256), dim3(256), 0, stream, xoh, recomb, cntf, FC4, FE);
  hipLaunchKernelGGL(k_gemm, dim3(8,16), dim3(256), 0, stream, gexp, W, part);
  hipLaunchKernelGGL(k_gemmreduce, dim3(125), dim3(256), 0, stream, part, bias, recomb, cntf, accp, BC4, BE);
  hipLaunchKernelGGL(k_chains, dim3(64), dim3(64), 0, stream, refB, FC4, BC4, FE, BE, Fb, Sb);
  hipLaunchKernelGGL(k_sites, dim3(MM*NB2/4), dim3(256), 0, stream, Fb, Sb, pack, obsw, accp, bias, term);
  hipLaunchKernelGGL(k_final, dim3(1), dim3(256), 0, stream, term, out);
}